// Round 8
// baseline (509.413 us; speedup 1.0000x reference)
//
#include <hip/hip_runtime.h>
#include <cstdint>
#include <cstddef>

typedef __attribute__((ext_vector_type(4))) float f32x4;
typedef __attribute__((ext_vector_type(8))) short s16x8;
typedef __attribute__((ext_vector_type(8))) _Float16 f16x8;
typedef __attribute__((ext_vector_type(4))) unsigned short u16x4;
typedef __attribute__((ext_vector_type(8))) unsigned short u16x8;

#define MFMA_BF16(a, b, c) __builtin_amdgcn_mfma_f32_16x16x32_bf16((a), (b), (c), 0, 0, 0)
#define MFMA_F16(a, b, c) __builtin_amdgcn_mfma_f32_16x16x32_f16((a), (b), (c), 0, 0, 0)
#define GLOAD_LDS16(src, dst)                                             \
  __builtin_amdgcn_global_load_lds(                                       \
      (const __attribute__((address_space(1))) void*)(src),               \
      (__attribute__((address_space(3))) void*)(dst), 16, 0, 0)

static constexpr int kD = 1024;
static constexpr int kT = 2048;

__device__ __forceinline__ unsigned short f2bf(float f) {
  union { float f; uint32_t u; } v; v.f = f;
  uint32_t r = v.u + 0x7fffu + ((v.u >> 16) & 1u);
  return (unsigned short)(r >> 16);
}
__device__ __forceinline__ unsigned short f2h(float f) {
  union { _Float16 h; unsigned short u; } cv;
  cv.h = (_Float16)f;
  return cv.u;
}

// ---------------------------------------------------------------------------
// Fused fp32 -> fp16/bf16 conversion for all 7 tensors.
// fp16: q, k, Wq, Wk (score path).  bf16: v, Wv, Wo (value path).
// ---------------------------------------------------------------------------
__global__ __launch_bounds__(256) void convert_all_k(
    const float* __restrict__ q, const float* __restrict__ k,
    const float* __restrict__ v, const float* __restrict__ Wq,
    const float* __restrict__ Wk, const float* __restrict__ Wv,
    const float* __restrict__ Wo, unsigned short* __restrict__ q_h,
    unsigned short* __restrict__ k_h, unsigned short* __restrict__ v_b,
    unsigned short* __restrict__ Wq_h, unsigned short* __restrict__ Wk_h,
    unsigned short* __restrict__ Wv_b, unsigned short* __restrict__ Wo_b) {
  constexpr int nq4 = (4 * 2048 * 1024) / 4;
  constexpr int nw4 = (1024 * 1024) / 4;
  constexpr int total = 3 * nq4 + 4 * nw4;
  for (int i = blockIdx.x * 256 + threadIdx.x; i < total; i += gridDim.x * 256) {
    const float* src;
    unsigned short* dst;
    int off;
    bool use_f16;
    if (i < nq4) { src = q; dst = q_h; off = i; use_f16 = true; }
    else if (i < 2 * nq4) { src = k; dst = k_h; off = i - nq4; use_f16 = true; }
    else if (i < 3 * nq4) { src = v; dst = v_b; off = i - 2 * nq4; use_f16 = false; }
    else if (i < 3 * nq4 + nw4) { src = Wq; dst = Wq_h; off = i - 3 * nq4; use_f16 = true; }
    else if (i < 3 * nq4 + 2 * nw4) { src = Wk; dst = Wk_h; off = i - 3 * nq4 - nw4; use_f16 = true; }
    else if (i < 3 * nq4 + 3 * nw4) { src = Wv; dst = Wv_b; off = i - 3 * nq4 - 2 * nw4; use_f16 = false; }
    else { src = Wo; dst = Wo_b; off = i - 3 * nq4 - 3 * nw4; use_f16 = false; }
    f32x4 vv = ((const f32x4*)src)[off];
    u16x4 o4;
#pragma unroll
    for (int j = 0; j < 4; j++) o4[j] = use_f16 ? f2h(vv[j]) : f2bf(vv[j]);
    ((u16x4*)dst)[off] = o4;
  }
}

// ---------------------------------------------------------------------------
// NT GEMM on pre-converted 16-bit operands: C = X @ W^T + bias.
// M=8192, N=K=1024. 128x128 tile, BK=64, 4 waves (2x2), 3 blocks/CU.
// MODE 0: f16 in (X,W), f16 out * oscale       (Q/K projections)
// MODE 1: bf16 in, bf16 out TRANSPOSED to vhT[B,H,64,T] (V projection)
// MODE 2: bf16 in, fp32 out + fp32 residual    (O projection)
// ---------------------------------------------------------------------------
template <int MODE>
__global__ __launch_bounds__(256, 3) void gemm_16(
    const unsigned short* __restrict__ X, const unsigned short* __restrict__ W,
    const float* __restrict__ bias, const float* __restrict__ resid,
    unsigned short* __restrict__ outB, float* __restrict__ outF, float oscale) {
  __shared__ unsigned short smem[MODE == 1 ? 16640 : 16384];
  unsigned short* Ah = smem;
  unsigned short* Bh = smem + 8192;

  const int tid = threadIdx.x, lane = tid & 63, w = tid >> 6;
  const int wg = (blockIdx.x & 7) * 64 + (blockIdx.x >> 3);
  const int m0 = (wg >> 3) * 128, n0 = (wg & 7) * 128;
  const int wm0 = (w >> 1) * 64, wn0 = (w & 1) * 64;
  const int lr = lane & 15, lk = lane >> 4;
  const int srow = lane >> 3, sslot = (lane & 7) ^ srow;

  const size_t xoff = (size_t)(m0 + w * 32 + srow) * kD + sslot * 8;
  const size_t woff = (size_t)(n0 + w * 32 + srow) * kD + sslot * 8;

  f32x4 acc[4][4];
#pragma unroll
  for (int i = 0; i < 4; i++)
#pragma unroll
    for (int j = 0; j < 4; j++) acc[i][j] = (f32x4){0.f, 0.f, 0.f, 0.f};

  for (int kt = 0; kt < kD / 64; ++kt) {
    __syncthreads();
    const int kof = kt * 64;
#pragma unroll
    for (int i = 0; i < 4; i++) {
      const int ldst = (w * 32 + i * 8) * 64;
      GLOAD_LDS16(X + xoff + (size_t)i * 8 * kD + kof, &Ah[ldst]);
      GLOAD_LDS16(W + woff + (size_t)i * 8 * kD + kof, &Bh[ldst]);
    }
    __syncthreads();
#pragma unroll
    for (int ks = 0; ks < 2; ks++) {
      s16x8 af[4], bf[4];
#pragma unroll
      for (int i = 0; i < 4; i++) {
        const int ra = wm0 + i * 16 + lr;
        const int oa = ra * 128 + ((((ks * 4) + lk) ^ (ra & 7)) << 4);
        const int rb = wn0 + i * 16 + lr;
        const int ob = rb * 128 + ((((ks * 4) + lk) ^ (rb & 7)) << 4);
        af[i] = *(const s16x8*)((const char*)Ah + oa);
        bf[i] = *(const s16x8*)((const char*)Bh + ob);
      }
#pragma unroll
      for (int i = 0; i < 4; i++)
#pragma unroll
        for (int j = 0; j < 4; j++) {
          if constexpr (MODE == 0) {
            acc[i][j] = MFMA_F16(*(const f16x8*)&af[i], *(const f16x8*)&bf[j],
                                 acc[i][j]);
          } else {
            acc[i][j] = MFMA_BF16(af[i], bf[j], acc[i][j]);
          }
        }
    }
  }

  if constexpr (MODE == 1) {
    // ---- transposed epilogue: write vhT[B,H,64,T] directly ----
    // stage tile into LDS as [col(d)][row(t)] with stride 130 (pad 2)
    __syncthreads();  // last loop barrier already passed; smem reads done
#pragma unroll
    for (int j = 0; j < 4; j++) {
      const int col = wn0 + j * 16 + lr;
      const float bv = bias[n0 + col];
#pragma unroll
      for (int i = 0; i < 4; i++)
#pragma unroll
        for (int r = 0; r < 4; r++) {
          const int row = wm0 + i * 16 + lk * 4 + r;
          smem[col * 130 + row] = f2bf(acc[i][j][r] + bv);
        }
    }
    __syncthreads();
    const int b = m0 >> 11, t0 = m0 & 2047;
    const int dl = tid >> 1, th = (tid & 1) * 64;
    const int h = (n0 + dl) >> 6, dh = (n0 + dl) & 63;
    unsigned short* dst = outB + ((size_t)((b * 16 + h) * 64 + dh)) * kT + t0 + th;
#pragma unroll
    for (int i = 0; i < 8; i++) {
      u16x8 o = *(const u16x8*)&smem[dl * 130 + th + i * 8];
      *(u16x8*)(dst + i * 8) = o;
    }
    return;
  }

#pragma unroll
  for (int j = 0; j < 4; j++) {
    const int col = n0 + wn0 + j * 16 + lr;
    const float bv = bias[col];
#pragma unroll
    for (int i = 0; i < 4; i++)
#pragma unroll
      for (int r = 0; r < 4; r++) {
        const int row = m0 + wm0 + i * 16 + lk * 4 + r;
        const size_t idx = (size_t)row * kD + col;
        float vv = acc[i][j][r] + bv;
        if constexpr (MODE == 0) {
          outB[idx] = f2h(vv * oscale);
        } else {
          outF[idx] = vv + resid[idx];
        }
      }
  }
}

// ---------------------------------------------------------------------------
// Fused attention, rebalanced.
// Loop A: K+V double-buffered; QK^T (fp16, swapped: lane owns q=lr);
//   p' = exp(s) unnormalized; l_part += p'; p'->bf16 -> per-wave p_w; PV MFMA.
// Epilogue A: rl = 1/l; attn_out = f2bf(pv * rl).
// Loop B: K-only staging; QK^T; p = exp(s)*rl; f32x4 nontemporal store.
// Block = 128 q-rows x one (b,h); 4 waves x 32 rows; K/V tiles of 64. 3/CU.
// ---------------------------------------------------------------------------
__global__ __launch_bounds__(256, 3) void attn_fused(
    const unsigned short* __restrict__ qh, const unsigned short* __restrict__ kh,
    const unsigned short* __restrict__ vhT, unsigned short* __restrict__ attn_out,
    float* __restrict__ attn_p) {
  __shared__ unsigned short kbuf[2][64 * 64];
  __shared__ unsigned short vbuf[2][64 * 64];
  __shared__ unsigned short qp[9216];  // Q staging (8192) then P tiles (4*32*72)

  const int tid = threadIdx.x, lane = tid & 63, w = tid >> 6;
  const int lr = lane & 15, lk = lane >> 4;
  const int srow = lane >> 3, sslot = (lane & 7) ^ srow;
  const int wg = (blockIdx.x & 7) * 128 + (blockIdx.x >> 3);
  const int bh = wg >> 4, qt = wg & 15;
  const int h = bh >> 2, b = bh & 3;  // bh = h*B + b -> matches output layout
  const int q0 = qt * 128, qm0 = w * 32;

  // ---- stage Q + K0 + V0 ----
  const size_t qsrc = (size_t)(b * kT + q0 + w * 32 + srow) * kD + h * 64 + sslot * 8;
#pragma unroll
  for (int i = 0; i < 4; i++)
    GLOAD_LDS16(qh + qsrc + (size_t)i * 8 * kD, &qp[(w * 32 + i * 8) * 64]);

  const size_t kbase = (size_t)(b * kT + w * 16 + srow) * kD + h * 64 + sslot * 8;
  const size_t vbase = ((size_t)((b * 16 + h) * 64) + w * 16 + srow) * kT + sslot * 8;

#pragma unroll
  for (int i = 0; i < 2; i++) {
    const int ldst = (w * 16 + i * 8) * 64;
    GLOAD_LDS16(kh + kbase + (size_t)(i * 8) * kD, &kbuf[0][ldst]);
    GLOAD_LDS16(vhT + vbase + (size_t)i * 8 * kT, &vbuf[0][ldst]);
  }
  __syncthreads();

  // Q fragments -> registers (qp LDS is reused for P)
  f16x8 qf[2][2];
#pragma unroll
  for (int mq = 0; mq < 2; mq++)
#pragma unroll
    for (int ks = 0; ks < 2; ks++) {
      const int rq = qm0 + mq * 16 + lr;
      qf[mq][ks] = *(const f16x8*)((const char*)qp + rq * 128 +
                                   ((((ks * 4) + lk) ^ (rq & 7)) << 4));
    }

  float l_part[2] = {0.f, 0.f};
  f32x4 pv[2][4];
#pragma unroll
  for (int mq = 0; mq < 2; mq++)
#pragma unroll
    for (int nd = 0; nd < 4; nd++) pv[mq][nd] = (f32x4){0.f, 0.f, 0.f, 0.f};
  unsigned short* p_w = &qp[w * 2304];  // 32 x 72 per wave

  // ============ loop A: denominators + unnormalized PV ============
  for (int kt = 0; kt < kT / 64; ++kt) {
    if (kt + 1 < kT / 64) {
#pragma unroll
      for (int i = 0; i < 2; i++) {
        const int ldst = (w * 16 + i * 8) * 64;
        GLOAD_LDS16(kh + kbase + (size_t)((kt + 1) * 64 + i * 8) * kD,
                    &kbuf[(kt + 1) & 1][ldst]);
        GLOAD_LDS16(vhT + vbase + (size_t)i * 8 * kT + (kt + 1) * 64,
                    &vbuf[(kt + 1) & 1][ldst]);
      }
    }
    const unsigned short* kb = kbuf[kt & 1];
    const unsigned short* vb = vbuf[kt & 1];
    f32x4 sc[2][4];
#pragma unroll
    for (int mq = 0; mq < 2; mq++)
#pragma unroll
      for (int ni = 0; ni < 4; ni++) sc[mq][ni] = (f32x4){0.f, 0.f, 0.f, 0.f};
#pragma unroll
    for (int ks = 0; ks < 2; ks++) {
      f16x8 kf[4];
#pragma unroll
      for (int ni = 0; ni < 4; ni++) {
        const int rk = ni * 16 + lr;
        kf[ni] = *(const f16x8*)((const char*)kb + rk * 128 +
                                 ((((ks * 4) + lk) ^ (rk & 7)) << 4));
      }
#pragma unroll
      for (int mq = 0; mq < 2; mq++)
#pragma unroll
        for (int ni = 0; ni < 4; ni++)
          sc[mq][ni] = MFMA_F16(kf[ni], qf[mq][ks], sc[mq][ni]);  // swapped
    }
    // p' = exp(s), accumulate l, convert to bf16 into p_w
#pragma unroll
    for (int mq = 0; mq < 2; mq++) {
#pragma unroll
      for (int ni = 0; ni < 4; ni++) {
        f32x4 pr;
#pragma unroll
        for (int r = 0; r < 4; r++) pr[r] = __expf(sc[mq][ni][r]);
        l_part[mq] += pr[0] + pr[1] + pr[2] + pr[3];
        uint32_t d0, d1;
        asm("v_cvt_pk_bf16_f32 %0, %1, %2" : "=v"(d0) : "v"(pr[0]), "v"(pr[1]));
        asm("v_cvt_pk_bf16_f32 %0, %1, %2" : "=v"(d1) : "v"(pr[2]), "v"(pr[3]));
        uint2 dd; dd.x = d0; dd.y = d1;
        *(uint2*)&p_w[(mq * 16 + lr) * 72 + ni * 16 + 4 * lk] = dd;
      }
    }
    // PV: per-wave P buffer (same-wave lgkm ordering)
#pragma unroll
    for (int ks = 0; ks < 2; ks++) {
      s16x8 pf[2], vf[4];
#pragma unroll
      for (int mq = 0; mq < 2; mq++)
        pf[mq] = *(const s16x8*)&p_w[(mq * 16 + lr) * 72 + ks * 32 + lk * 8];
#pragma unroll
      for (int nd = 0; nd < 4; nd++) {
        const int row = nd * 16 + lr;
        const int sw2 = ((ks * 4) + lk) ^ (row & 7);
        vf[nd] = *(const s16x8*)((const char*)vb + row * 128 + (sw2 << 4));
      }
#pragma unroll
      for (int mq = 0; mq < 2; mq++)
#pragma unroll
        for (int nd = 0; nd < 4; nd++)
          pv[mq][nd] = MFMA_BF16(pf[mq], vf[nd], pv[mq][nd]);
    }
    __syncthreads();
  }

  // reduce l across the 4 lane-groups sharing q=lr; write attn_out
  float rl[2];
#pragma unroll
  for (int mq = 0; mq < 2; mq++) {
    float s = l_part[mq];
    s += __shfl_xor(s, 16, 64);
    s += __shfl_xor(s, 32, 64);
    rl[mq] = 1.0f / s;
  }
  // pv C-layout: row(q-local) = lk*4+r, col(d) = nd*16+lr; scale by that row's rl
  // NOTE: pv rows belong to q = lk*4+r, whose rl lives in lanes sharing lr=q...
  // rl here is indexed by THIS lane's q=lr ownership from the swapped-QK layout,
  // but pv needs rl for q=lk*4+r. Broadcast via shuffle: rl_q = shfl(rl, q-row).
#pragma unroll
  for (int mq = 0; mq < 2; mq++)
#pragma unroll
    for (int r = 0; r < 4; r++) {
      const int qloc = lk * 4 + r;
      const float rlq = __shfl(rl[mq], qloc, 64);  // lane qloc holds q=qloc's rl
#pragma unroll
      for (int nd = 0; nd < 4; nd++) {
        const int qrow = q0 + qm0 + mq * 16 + qloc;
        attn_out[((size_t)(b * kT + qrow)) * kD + h * 64 + nd * 16 + lr] =
            f2bf(pv[mq][nd][r] * rlq);
      }
    }

  // ============ loop B: probs streaming ============
#pragma unroll
  for (int i = 0; i < 2; i++)
    GLOAD_LDS16(kh + kbase + (size_t)(i * 8) * kD, &kbuf[0][(w * 16 + i * 8) * 64]);
  __syncthreads();

  for (int kt = 0; kt < kT / 64; ++kt) {
    if (kt + 1 < kT / 64) {
#pragma unroll
      for (int i = 0; i < 2; i++)
        GLOAD_LDS16(kh + kbase + (size_t)((kt + 1) * 64 + i * 8) * kD,
                    &kbuf[(kt + 1) & 1][(w * 16 + i * 8) * 64]);
    }
    const unsigned short* kb = kbuf[kt & 1];
    f32x4 sc[2][4];
#pragma unroll
    for (int mq = 0; mq < 2; mq++)
#pragma unroll
      for (int ni = 0; ni < 4; ni++) sc[mq][ni] = (f32x4){0.f, 0.f, 0.f, 0.f};
#pragma unroll
    for (int ks = 0; ks < 2; ks++) {
      f16x8 kf[4];
#pragma unroll
      for (int ni = 0; ni < 4; ni++) {
        const int rk = ni * 16 + lr;
        kf[ni] = *(const f16x8*)((const char*)kb + rk * 128 +
                                 ((((ks * 4) + lk) ^ (rk & 7)) << 4));
      }
#pragma unroll
      for (int mq = 0; mq < 2; mq++)
#pragma unroll
        for (int ni = 0; ni < 4; ni++)
          sc[mq][ni] = MFMA_F16(kf[ni], qf[mq][ks], sc[mq][ni]);  // swapped
    }
#pragma unroll
    for (int mq = 0; mq < 2; mq++) {
      const int qrow = q0 + qm0 + mq * 16 + lr;
      float* prow = attn_p + ((size_t)(bh * kT + qrow)) * kT + kt * 64 + 4 * lk;
#pragma unroll
      for (int ni = 0; ni < 4; ni++) {
        f32x4 pr;
#pragma unroll
        for (int r = 0; r < 4; r++) pr[r] = __expf(sc[mq][ni][r]) * rl[mq];
        __builtin_nontemporal_store(pr, (f32x4*)(prow + ni * 16));
      }
    }
    __syncthreads();
  }
}

// ---------------------------------------------------------------------------
// Row LayerNorm
// ---------------------------------------------------------------------------
__global__ __launch_bounds__(256) void ln_kernel(
    const float* __restrict__ x, const float* __restrict__ gamma,
    const float* __restrict__ beta, float* __restrict__ out) {
  __shared__ float ssum[4], ssq[4];
  const int row = blockIdx.x, tid = threadIdx.x;
  f32x4 v = *(const f32x4*)&x[(size_t)row * kD + tid * 4];
  float s = v[0] + v[1] + v[2] + v[3];
  float q2 = v[0] * v[0] + v[1] * v[1] + v[2] * v[2] + v[3] * v[3];
#pragma unroll
  for (int d = 1; d < 64; d <<= 1) {
    s += __shfl_xor(s, d, 64);
    q2 += __shfl_xor(q2, d, 64);
  }
  const int w = tid >> 6, lane = tid & 63;
  if (lane == 0) {
    ssum[w] = s;
    ssq[w] = q2;
  }
  __syncthreads();
  s = ssum[0] + ssum[1] + ssum[2] + ssum[3];
  q2 = ssq[0] + ssq[1] + ssq[2] + ssq[3];
  const float mu = s * (1.f / 1024.f);
  const float var = q2 * (1.f / 1024.f) - mu * mu;
  const float rstd = rsqrtf(var + 1e-5f);
  f32x4 g = *(const f32x4*)&gamma[tid * 4];
  f32x4 bb = *(const f32x4*)&beta[tid * 4];
  f32x4 o;
#pragma unroll
  for (int j = 0; j < 4; j++) o[j] = (v[j] - mu) * rstd * g[j] + bb[j];
  *(f32x4*)&out[(size_t)row * kD + tid * 4] = o;
}

// ---------------------------------------------------------------------------
extern "C" void kernel_launch(void* const* d_in, const int* in_sizes, int n_in,
                              void* d_out, int out_size, void* d_ws,
                              size_t ws_size, hipStream_t stream) {
  const float* q = (const float*)d_in[0];
  const float* k = (const float*)d_in[1];
  const float* v = (const float*)d_in[2];
  const float* Wq = (const float*)d_in[3];
  const float* bq = (const float*)d_in[4];
  const float* Wk = (const float*)d_in[5];
  const float* bk = (const float*)d_in[6];
  const float* Wv = (const float*)d_in[7];
  const float* bv = (const float*)d_in[8];
  const float* Wo = (const float*)d_in[9];
  const float* bo = (const float*)d_in[10];
  const float* gamma = (const float*)d_in[11];
  const float* beta = (const float*)d_in[12];

  float* out = (float*)d_out;
  float* attn_p = out + (size_t)8192 * 1024;

  constexpr size_t NQ = (size_t)4 * 2048 * 1024;  // 8.4M elems
  constexpr size_t NW = (size_t)1024 * 1024;

  unsigned short* w16 = (unsigned short*)d_ws;
  unsigned short* q_h  = w16 + 0 * NQ;
  unsigned short* k_h  = w16 + 1 * NQ;
  unsigned short* v_b  = w16 + 2 * NQ;
  unsigned short* qh_h = w16 + 3 * NQ;
  unsigned short* kh_h = w16 + 4 * NQ;
  unsigned short* vhT  = w16 + 5 * NQ;
  unsigned short* ao_b = w16 + 6 * NQ;
  unsigned short* Wq_h = w16 + 7 * NQ;
  unsigned short* Wk_h = Wq_h + NW;
  unsigned short* Wv_b = Wq_h + 2 * NW;
  unsigned short* Wo_b = Wq_h + 3 * NW;
  float* xbuf = (float*)(Wq_h + 4 * NW);

  dim3 blk(256);
  convert_all_k<<<2048, blk, 0, stream>>>(q, k, v, Wq, Wk, Wv, Wo, q_h, k_h,
                                          v_b, Wq_h, Wk_h, Wv_b, Wo_b);

  // Q-proj folds the 1/temperature = 1/8 scale into the stored fp16 result.
  gemm_16<0><<<512, blk, 0, stream>>>(q_h, Wq_h, bq, nullptr, qh_h, nullptr,
                                      0.125f);
  gemm_16<0><<<512, blk, 0, stream>>>(k_h, Wk_h, bk, nullptr, kh_h, nullptr,
                                      1.0f);
  gemm_16<1><<<512, blk, 0, stream>>>(v_b, Wv_b, bv, nullptr, vhT, nullptr,
                                      1.0f);
  attn_fused<<<1024, blk, 0, stream>>>(qh_h, kh_h, vhT, ao_b, attn_p);
  gemm_16<2><<<512, blk, 0, stream>>>(ao_b, Wo_b, bo, q, nullptr, xbuf, 1.0f);
  ln_kernel<<<8192, blk, 0, stream>>>(xbuf, gamma, beta, out);
}

// Round 11
// 507.669 us; speedup vs baseline: 1.0034x; 1.0034x over previous
//
#include <hip/hip_runtime.h>
#include <cstdint>
#include <cstddef>

typedef __attribute__((ext_vector_type(4))) float f32x4;
typedef __attribute__((ext_vector_type(8))) short s16x8;
typedef __attribute__((ext_vector_type(8))) _Float16 f16x8;
typedef __attribute__((ext_vector_type(4))) unsigned short u16x4;
typedef __attribute__((ext_vector_type(8))) unsigned short u16x8;

#define MFMA_BF16(a, b, c) __builtin_amdgcn_mfma_f32_16x16x32_bf16((a), (b), (c), 0, 0, 0)
#define MFMA_F16(a, b, c) __builtin_amdgcn_mfma_f32_16x16x32_f16((a), (b), (c), 0, 0, 0)
#define GLOAD_LDS16(src, dst)                                             \
  __builtin_amdgcn_global_load_lds(                                       \
      (const __attribute__((address_space(1))) void*)(src),               \
      (__attribute__((address_space(3))) void*)(dst), 16, 0, 0)

static constexpr int kD = 1024;
static constexpr int kT = 2048;

__device__ __forceinline__ unsigned short f2bf(float f) {
  union { float f; uint32_t u; } v; v.f = f;
  uint32_t r = v.u + 0x7fffu + ((v.u >> 16) & 1u);
  return (unsigned short)(r >> 16);
}
__device__ __forceinline__ unsigned short f2h(float f) {
  union { _Float16 h; unsigned short u; } cv;
  cv.h = (_Float16)f;
  return cv.u;
}

// ---------------------------------------------------------------------------
// Fused fp32 -> fp16/bf16 conversion for all 7 tensors.
// fp16: q, k, Wq, Wk (score path).  bf16: v, Wv, Wo (value path).
// ---------------------------------------------------------------------------
__global__ __launch_bounds__(256) void convert_all_k(
    const float* __restrict__ q, const float* __restrict__ k,
    const float* __restrict__ v, const float* __restrict__ Wq,
    const float* __restrict__ Wk, const float* __restrict__ Wv,
    const float* __restrict__ Wo, unsigned short* __restrict__ q_h,
    unsigned short* __restrict__ k_h, unsigned short* __restrict__ v_b,
    unsigned short* __restrict__ Wq_h, unsigned short* __restrict__ Wk_h,
    unsigned short* __restrict__ Wv_b, unsigned short* __restrict__ Wo_b) {
  constexpr int nq4 = (4 * 2048 * 1024) / 4;
  constexpr int nw4 = (1024 * 1024) / 4;
  constexpr int total = 3 * nq4 + 4 * nw4;
  for (int i = blockIdx.x * 256 + threadIdx.x; i < total; i += gridDim.x * 256) {
    const float* src;
    unsigned short* dst;
    int off;
    bool use_f16;
    if (i < nq4) { src = q; dst = q_h; off = i; use_f16 = true; }
    else if (i < 2 * nq4) { src = k; dst = k_h; off = i - nq4; use_f16 = true; }
    else if (i < 3 * nq4) { src = v; dst = v_b; off = i - 2 * nq4; use_f16 = false; }
    else if (i < 3 * nq4 + nw4) { src = Wq; dst = Wq_h; off = i - 3 * nq4; use_f16 = true; }
    else if (i < 3 * nq4 + 2 * nw4) { src = Wk; dst = Wk_h; off = i - 3 * nq4 - nw4; use_f16 = true; }
    else if (i < 3 * nq4 + 3 * nw4) { src = Wv; dst = Wv_b; off = i - 3 * nq4 - 2 * nw4; use_f16 = false; }
    else { src = Wo; dst = Wo_b; off = i - 3 * nq4 - 3 * nw4; use_f16 = false; }
    f32x4 vv = ((const f32x4*)src)[off];
    u16x4 o4;
#pragma unroll
    for (int j = 0; j < 4; j++) o4[j] = use_f16 ? f2h(vv[j]) : f2bf(vv[j]);
    ((u16x4*)dst)[off] = o4;
  }
}

// ---------------------------------------------------------------------------
// NT GEMM on pre-converted 16-bit operands: C = X @ W^T + bias.
// M=8192, N=K=1024. 128x128 tile, BK=64, 4 waves (2x2), 3 blocks/CU.
// MODE 0: f16 in, f16 out * oscale       (Q/K projections)
// MODE 1: bf16 in, bf16 out transposed to vhT[B,H,64,T] (V projection)
// MODE 2: bf16 in, fp32 out + fp32 residual (O projection)
// ---------------------------------------------------------------------------
template <int MODE>
__global__ __launch_bounds__(256, 3) void gemm_16(
    const unsigned short* __restrict__ X, const unsigned short* __restrict__ W,
    const float* __restrict__ bias, const float* __restrict__ resid,
    unsigned short* __restrict__ outB, float* __restrict__ outF, float oscale) {
  __shared__ unsigned short smem[MODE == 1 ? 16640 : 16384];
  unsigned short* Ah = smem;
  unsigned short* Bh = smem + 8192;

  const int tid = threadIdx.x, lane = tid & 63, w = tid >> 6;
  const int wg = (blockIdx.x & 7) * 64 + (blockIdx.x >> 3);
  const int m0 = (wg >> 3) * 128, n0 = (wg & 7) * 128;
  const int wm0 = (w >> 1) * 64, wn0 = (w & 1) * 64;
  const int lr = lane & 15, lk = lane >> 4;
  const int srow = lane >> 3, sslot = (lane & 7) ^ srow;

  const size_t xoff = (size_t)(m0 + w * 32 + srow) * kD + sslot * 8;
  const size_t woff = (size_t)(n0 + w * 32 + srow) * kD + sslot * 8;

  f32x4 acc[4][4];
#pragma unroll
  for (int i = 0; i < 4; i++)
#pragma unroll
    for (int j = 0; j < 4; j++) acc[i][j] = (f32x4){0.f, 0.f, 0.f, 0.f};

  for (int kt = 0; kt < kD / 64; ++kt) {
    __syncthreads();
    const int kof = kt * 64;
#pragma unroll
    for (int i = 0; i < 4; i++) {
      const int ldst = (w * 32 + i * 8) * 64;
      GLOAD_LDS16(X + xoff + (size_t)i * 8 * kD + kof, &Ah[ldst]);
      GLOAD_LDS16(W + woff + (size_t)i * 8 * kD + kof, &Bh[ldst]);
    }
    __syncthreads();
#pragma unroll
    for (int ks = 0; ks < 2; ks++) {
      s16x8 af[4], bf[4];
#pragma unroll
      for (int i = 0; i < 4; i++) {
        const int ra = wm0 + i * 16 + lr;
        const int oa = ra * 128 + ((((ks * 4) + lk) ^ (ra & 7)) << 4);
        const int rb = wn0 + i * 16 + lr;
        const int ob = rb * 128 + ((((ks * 4) + lk) ^ (rb & 7)) << 4);
        af[i] = *(const s16x8*)((const char*)Ah + oa);
        bf[i] = *(const s16x8*)((const char*)Bh + ob);
      }
#pragma unroll
      for (int i = 0; i < 4; i++)
#pragma unroll
        for (int j = 0; j < 4; j++) {
          if constexpr (MODE == 0) {
            acc[i][j] = MFMA_F16(*(const f16x8*)&af[i], *(const f16x8*)&bf[j],
                                 acc[i][j]);
          } else {
            acc[i][j] = MFMA_BF16(af[i], bf[j], acc[i][j]);
          }
        }
    }
  }

  if constexpr (MODE == 1) {
    // transposed epilogue: stage [d][t] with stride 130, write vhT coalesced
    __syncthreads();
#pragma unroll
    for (int j = 0; j < 4; j++) {
      const int col = wn0 + j * 16 + lr;
      const float bv = bias[n0 + col];
#pragma unroll
      for (int i = 0; i < 4; i++)
#pragma unroll
        for (int r = 0; r < 4; r++) {
          const int row = wm0 + i * 16 + lk * 4 + r;
          smem[col * 130 + row] = f2bf(acc[i][j][r] + bv);
        }
    }
    __syncthreads();
    const int b = m0 >> 11, t0 = m0 & 2047;
    const int dl = tid >> 1, th = (tid & 1) * 64;
    const int h = (n0 + dl) >> 6, dh = (n0 + dl) & 63;
    unsigned short* dst = outB + ((size_t)((b * 16 + h) * 64 + dh)) * kT + t0 + th;
#pragma unroll
    for (int i = 0; i < 8; i++) {
      u16x8 o = *(const u16x8*)&smem[dl * 130 + th + i * 8];
      *(u16x8*)(dst + i * 8) = o;
    }
    return;
  }

#pragma unroll
  for (int j = 0; j < 4; j++) {
    const int col = n0 + wn0 + j * 16 + lr;
    const float bv = bias[col];
#pragma unroll
    for (int i = 0; i < 4; i++)
#pragma unroll
      for (int r = 0; r < 4; r++) {
        const int row = m0 + wm0 + i * 16 + lk * 4 + r;
        const size_t idx = (size_t)row * kD + col;
        float vv = acc[i][j][r] + bv;
        if constexpr (MODE == 0) {
          outB[idx] = f2h(vv * oscale);
        } else {
          outF[idx] = vv + resid[idx];
        }
      }
  }
}

// ---------------------------------------------------------------------------
// Fused attention, rebalanced.
// Loop A: K+V double-buffered; QK^T (fp16, swapped: lane owns q=lr);
//   p' = exp(s) unnormalized; l_part += p'; p'->bf16 -> per-wave p_w; PV MFMA.
// Epilogue A: rl = 1/l; attn_out = f2bf(pv * rl).
// Loop B: K-only staging; QK^T; p = exp(s)*rl; f32x4 nontemporal store.
// Block = 128 q-rows x one (b,h); 4 waves x 32 rows; K/V tiles of 64. 3/CU.
// ---------------------------------------------------------------------------
__global__ __launch_bounds__(256, 3) void attn_fused(
    const unsigned short* __restrict__ qh, const unsigned short* __restrict__ kh,
    const unsigned short* __restrict__ vhT, unsigned short* __restrict__ attn_out,
    float* __restrict__ attn_p) {
  __shared__ unsigned short kbuf[2][64 * 64];
  __shared__ unsigned short vbuf[2][64 * 64];
  __shared__ unsigned short qp[9216];  // Q staging (8192) then P tiles (4*32*72)

  const int tid = threadIdx.x, lane = tid & 63, w = tid >> 6;
  const int lr = lane & 15, lk = lane >> 4;
  const int srow = lane >> 3, sslot = (lane & 7) ^ srow;
  const int wg = (blockIdx.x & 7) * 128 + (blockIdx.x >> 3);
  const int bh = wg >> 4, qt = wg & 15;
  const int h = bh >> 2, b = bh & 3;  // bh = h*B + b -> matches output layout
  const int q0 = qt * 128, qm0 = w * 32;

  // ---- stage Q + K0 + V0 ----
  const size_t qsrc = (size_t)(b * kT + q0 + w * 32 + srow) * kD + h * 64 + sslot * 8;
#pragma unroll
  for (int i = 0; i < 4; i++)
    GLOAD_LDS16(qh + qsrc + (size_t)i * 8 * kD, &qp[(w * 32 + i * 8) * 64]);

  const size_t kbase = (size_t)(b * kT + w * 16 + srow) * kD + h * 64 + sslot * 8;
  const size_t vbase = ((size_t)((b * 16 + h) * 64) + w * 16 + srow) * kT + sslot * 8;

#pragma unroll
  for (int i = 0; i < 2; i++) {
    const int ldst = (w * 16 + i * 8) * 64;
    GLOAD_LDS16(kh + kbase + (size_t)(i * 8) * kD, &kbuf[0][ldst]);
    GLOAD_LDS16(vhT + vbase + (size_t)i * 8 * kT, &vbuf[0][ldst]);
  }
  __syncthreads();

  // Q fragments -> registers (qp LDS is reused for P)
  f16x8 qf[2][2];
#pragma unroll
  for (int mq = 0; mq < 2; mq++)
#pragma unroll
    for (int ks = 0; ks < 2; ks++) {
      const int rq = qm0 + mq * 16 + lr;
      qf[mq][ks] = *(const f16x8*)((const char*)qp + rq * 128 +
                                   ((((ks * 4) + lk) ^ (rq & 7)) << 4));
    }

  float l_part[2] = {0.f, 0.f};
  f32x4 pv[2][4];
#pragma unroll
  for (int mq = 0; mq < 2; mq++)
#pragma unroll
    for (int nd = 0; nd < 4; nd++) pv[mq][nd] = (f32x4){0.f, 0.f, 0.f, 0.f};
  unsigned short* p_w = &qp[w * 2304];  // 32 x 72 per wave

  // ============ loop A: denominators + unnormalized PV ============
  for (int kt = 0; kt < kT / 64; ++kt) {
    if (kt + 1 < kT / 64) {
#pragma unroll
      for (int i = 0; i < 2; i++) {
        const int ldst = (w * 16 + i * 8) * 64;
        GLOAD_LDS16(kh + kbase + (size_t)((kt + 1) * 64 + i * 8) * kD,
                    &kbuf[(kt + 1) & 1][ldst]);
        GLOAD_LDS16(vhT + vbase + (size_t)i * 8 * kT + (kt + 1) * 64,
                    &vbuf[(kt + 1) & 1][ldst]);
      }
    }
    const unsigned short* kb = kbuf[kt & 1];
    const unsigned short* vb = vbuf[kt & 1];
    f32x4 sc[2][4];
#pragma unroll
    for (int mq = 0; mq < 2; mq++)
#pragma unroll
      for (int ni = 0; ni < 4; ni++) sc[mq][ni] = (f32x4){0.f, 0.f, 0.f, 0.f};
#pragma unroll
    for (int ks = 0; ks < 2; ks++) {
      f16x8 kf[4];
#pragma unroll
      for (int ni = 0; ni < 4; ni++) {
        const int rk = ni * 16 + lr;
        kf[ni] = *(const f16x8*)((const char*)kb + rk * 128 +
                                 ((((ks * 4) + lk) ^ (rk & 7)) << 4));
      }
#pragma unroll
      for (int mq = 0; mq < 2; mq++)
#pragma unroll
        for (int ni = 0; ni < 4; ni++)
          sc[mq][ni] = MFMA_F16(kf[ni], qf[mq][ks], sc[mq][ni]);  // swapped
    }
    // p' = exp(s), accumulate l, convert to bf16 into p_w
#pragma unroll
    for (int mq = 0; mq < 2; mq++) {
#pragma unroll
      for (int ni = 0; ni < 4; ni++) {
        f32x4 pr;
#pragma unroll
        for (int r = 0; r < 4; r++) pr[r] = __expf(sc[mq][ni][r]);
        l_part[mq] += pr[0] + pr[1] + pr[2] + pr[3];
        uint32_t d0, d1;
        asm("v_cvt_pk_bf16_f32 %0, %1, %2" : "=v"(d0) : "v"(pr[0]), "v"(pr[1]));
        asm("v_cvt_pk_bf16_f32 %0, %1, %2" : "=v"(d1) : "v"(pr[2]), "v"(pr[3]));
        uint2 dd; dd.x = d0; dd.y = d1;
        *(uint2*)&p_w[(mq * 16 + lr) * 72 + ni * 16 + 4 * lk] = dd;
      }
    }
    // PV: per-wave P buffer (same-wave lgkm ordering)
#pragma unroll
    for (int ks = 0; ks < 2; ks++) {
      s16x8 pf[2], vf[4];
#pragma unroll
      for (int mq = 0; mq < 2; mq++)
        pf[mq] = *(const s16x8*)&p_w[(mq * 16 + lr) * 72 + ks * 32 + lk * 8];
#pragma unroll
      for (int nd = 0; nd < 4; nd++) {
        const int row = nd * 16 + lr;
        const int sw2 = ((ks * 4) + lk) ^ (row & 7);
        vf[nd] = *(const s16x8*)((const char*)vb + row * 128 + (sw2 << 4));
      }
#pragma unroll
      for (int mq = 0; mq < 2; mq++)
#pragma unroll
        for (int nd = 0; nd < 4; nd++)
          pv[mq][nd] = MFMA_BF16(pf[mq], vf[nd], pv[mq][nd]);
    }
    __syncthreads();
  }

  // reduce l across the 4 lane-groups sharing q=lr; write attn_out
  float rl[2];
#pragma unroll
  for (int mq = 0; mq < 2; mq++) {
    float s = l_part[mq];
    s += __shfl_xor(s, 16, 64);
    s += __shfl_xor(s, 32, 64);
    rl[mq] = 1.0f / s;
  }
  // pv C-layout: row(q-local) = lk*4+r, col(d) = nd*16+lr; broadcast that
  // row's rl from lane qloc (which owns q=qloc in the swapped-QK layout).
#pragma unroll
  for (int mq = 0; mq < 2; mq++)
#pragma unroll
    for (int r = 0; r < 4; r++) {
      const int qloc = lk * 4 + r;
      const float rlq = __shfl(rl[mq], qloc, 64);
#pragma unroll
      for (int nd = 0; nd < 4; nd++) {
        const int qrow = q0 + qm0 + mq * 16 + qloc;
        attn_out[((size_t)(b * kT + qrow)) * kD + h * 64 + nd * 16 + lr] =
            f2bf(pv[mq][nd][r] * rlq);
      }
    }

  // ============ loop B: probs streaming ============
#pragma unroll
  for (int i = 0; i < 2; i++)
    GLOAD_LDS16(kh + kbase + (size_t)(i * 8) * kD, &kbuf[0][(w * 16 + i * 8) * 64]);
  __syncthreads();

  for (int kt = 0; kt < kT / 64; ++kt) {
    if (kt + 1 < kT / 64) {
#pragma unroll
      for (int i = 0; i < 2; i++)
        GLOAD_LDS16(kh + kbase + (size_t)((kt + 1) * 64 + i * 8) * kD,
                    &kbuf[(kt + 1) & 1][(w * 16 + i * 8) * 64]);
    }
    const unsigned short* kb = kbuf[kt & 1];
    f32x4 sc[2][4];
#pragma unroll
    for (int mq = 0; mq < 2; mq++)
#pragma unroll
      for (int ni = 0; ni < 4; ni++) sc[mq][ni] = (f32x4){0.f, 0.f, 0.f, 0.f};
#pragma unroll
    for (int ks = 0; ks < 2; ks++) {
      f16x8 kf[4];
#pragma unroll
      for (int ni = 0; ni < 4; ni++) {
        const int rk = ni * 16 + lr;
        kf[ni] = *(const f16x8*)((const char*)kb + rk * 128 +
                                 ((((ks * 4) + lk) ^ (rk & 7)) << 4));
      }
#pragma unroll
      for (int mq = 0; mq < 2; mq++)
#pragma unroll
        for (int ni = 0; ni < 4; ni++)
          sc[mq][ni] = MFMA_F16(kf[ni], qf[mq][ks], sc[mq][ni]);  // swapped
    }
#pragma unroll
    for (int mq = 0; mq < 2; mq++) {
      const int qrow = q0 + qm0 + mq * 16 + lr;
      float* prow = attn_p + ((size_t)(bh * kT + qrow)) * kT + kt * 64 + 4 * lk;
#pragma unroll
      for (int ni = 0; ni < 4; ni++) {
        f32x4 pr;
#pragma unroll
        for (int r = 0; r < 4; r++) pr[r] = __expf(sc[mq][ni][r]) * rl[mq];
        __builtin_nontemporal_store(pr, (f32x4*)(prow + ni * 16));
      }
    }
    __syncthreads();
  }
}

// ---------------------------------------------------------------------------
// Row LayerNorm
// ---------------------------------------------------------------------------
__global__ __launch_bounds__(256) void ln_kernel(
    const float* __restrict__ x, const float* __restrict__ gamma,
    const float* __restrict__ beta, float* __restrict__ out) {
  __shared__ float ssum[4], ssq[4];
  const int row = blockIdx.x, tid = threadIdx.x;
  f32x4 v = *(const f32x4*)&x[(size_t)row * kD + tid * 4];
  float s = v[0] + v[1] + v[2] + v[3];
  float q2 = v[0] * v[0] + v[1] * v[1] + v[2] * v[2] + v[3] * v[3];
#pragma unroll
  for (int d = 1; d < 64; d <<= 1) {
    s += __shfl_xor(s, d, 64);
    q2 += __shfl_xor(q2, d, 64);
  }
  const int w = tid >> 6, lane = tid & 63;
  if (lane == 0) {
    ssum[w] = s;
    ssq[w] = q2;
  }
  __syncthreads();
  s = ssum[0] + ssum[1] + ssum[2] + ssum[3];
  q2 = ssq[0] + ssq[1] + ssq[2] + ssq[3];
  const float mu = s * (1.f / 1024.f);
  const float var = q2 * (1.f / 1024.f) - mu * mu;
  const float rstd = rsqrtf(var + 1e-5f);
  f32x4 g = *(const f32x4*)&gamma[tid * 4];
  f32x4 bb = *(const f32x4*)&beta[tid * 4];
  f32x4 o;
#pragma unroll
  for (int j = 0; j < 4; j++) o[j] = (v[j] - mu) * rstd * g[j] + bb[j];
  *(f32x4*)&out[(size_t)row * kD + tid * 4] = o;
}

// ---------------------------------------------------------------------------
extern "C" void kernel_launch(void* const* d_in, const int* in_sizes, int n_in,
                              void* d_out, int out_size, void* d_ws,
                              size_t ws_size, hipStream_t stream) {
  const float* q = (const float*)d_in[0];
  const float* k = (const float*)d_in[1];
  const float* v = (const float*)d_in[2];
  const float* Wq = (const float*)d_in[3];
  const float* bq = (const float*)d_in[4];
  const float* Wk = (const float*)d_in[5];
  const float* bk = (const float*)d_in[6];
  const float* Wv = (const float*)d_in[7];
  const float* bv = (const float*)d_in[8];
  const float* Wo = (const float*)d_in[9];
  const float* bo = (const float*)d_in[10];
  const float* gamma = (const float*)d_in[11];
  const float* beta = (const float*)d_in[12];

  float* out = (float*)d_out;
  float* attn_p = out + (size_t)8192 * 1024;

  constexpr size_t NQ = (size_t)4 * 2048 * 1024;  // 8.4M elems
  constexpr size_t NW = (size_t)1024 * 1024;

  unsigned short* w16 = (unsigned short*)d_ws;
  unsigned short* q_h  = w16 + 0 * NQ;
  unsigned short* k_h  = w16 + 1 * NQ;
  unsigned short* v_b  = w16 + 2 * NQ;
  unsigned short* qh_h = w16 + 3 * NQ;
  unsigned short* kh_h = w16 + 4 * NQ;
  unsigned short* vhT  = w16 + 5 * NQ;
  unsigned short* ao_b = w16 + 6 * NQ;
  unsigned short* Wq_h = w16 + 7 * NQ;
  unsigned short* Wk_h = Wq_h + NW;
  unsigned short* Wv_b = Wq_h + 2 * NW;
  unsigned short* Wo_b = Wq_h + 3 * NW;
  float* xbuf = (float*)(Wq_h + 4 * NW);

  dim3 blk(256);
  convert_all_k<<<2048, blk, 0, stream>>>(q, k, v, Wq, Wk, Wv, Wo, q_h, k_h,
                                          v_b, Wq_h, Wk_h, Wv_b, Wo_b);

  // Q-proj folds the 1/temperature = 1/8 scale into the stored fp16 result.
  gemm_16<0><<<512, blk, 0, stream>>>(q_h, Wq_h, bq, nullptr, qh_h, nullptr,
                                      0.125f);
  gemm_16<0><<<512, blk, 0, stream>>>(k_h, Wk_h, bk, nullptr, kh_h, nullptr,
                                      1.0f);
  gemm_16<1><<<512, blk, 0, stream>>>(v_b, Wv_b, bv, nullptr, vhT, nullptr,
                                      1.0f);
  attn_fused<<<1024, blk, 0, stream>>>(qh_h, kh_h, vhT, ao_b, attn_p);
  gemm_16<2><<<512, blk, 0, stream>>>(ao_b, Wo_b, bo, q, nullptr, xbuf, 1.0f);
  ln_kernel<<<8192, blk, 0, stream>>>(xbuf, gamma, beta, out);
}